// Round 13
// baseline (346.411 us; speedup 1.0000x reference)
//
#include <hip/hip_runtime.h>
#include <hip/hip_bf16.h>
#include <hip/hip_fp8.h>
#include <math.h>

#define NB 4
#define NN 4096
#define UU 512

using short8   = __attribute__((ext_vector_type(8))) short;
using bf16x8   = __attribute__((ext_vector_type(8))) __bf16;
using floatx4  = __attribute__((ext_vector_type(4))) float;
using floatx16 = __attribute__((ext_vector_type(16))) float;

__device__ __forceinline__ floatx4 mfma16(short8 a, short8 b, floatx4 c) {
    return __builtin_amdgcn_mfma_f32_16x16x32_bf16(
        __builtin_bit_cast(bf16x8, a), __builtin_bit_cast(bf16x8, b), c, 0, 0, 0);
}
__device__ __forceinline__ floatx4 mfma16f8(long a, long b, floatx4 c) {
    return __builtin_amdgcn_mfma_f32_16x16x32_fp8_fp8(a, b, c, 0, 0, 0);
}
__device__ __forceinline__ floatx16 mfma32f8(long a, long b, floatx16 c) {
    return __builtin_amdgcn_mfma_f32_32x32x16_fp8_fp8(a, b, c, 0, 0, 0);
}

__device__ __forceinline__ unsigned short f2bf(float f) {
    union { float f; unsigned u; } v; v.f = f;
    return (unsigned short)((v.u + 0x7fffu + ((v.u >> 16) & 1u)) >> 16);
}
__device__ __forceinline__ float bf2f(unsigned short s) {
    union { unsigned u; float f; } v; v.u = ((unsigned)s) << 16; return v.f;
}
__device__ __forceinline__ unsigned char f2fp8(float f) {
    __hip_fp8_e4m3 v(f);
    return (unsigned char)v.__x;
}
__device__ __forceinline__ float fp82f(unsigned char c) {
    __hip_fp8_e4m3 v;
    v.__x = (__hip_fp8_storage_t)c;
    return (float)v;
}

#define GLL16(gp, lp) __builtin_amdgcn_global_load_lds( \
    (const __attribute__((address_space(1))) void*)(gp), \
    (__attribute__((address_space(3))) void*)(lp), 16, 0, 0)

// ---------------------------------------------------------------- converts
__global__ void __launch_bounds__(256) k_cvt_x(const float* __restrict__ x,
                                               unsigned short* __restrict__ xb) {
    int i = (blockIdx.x * 256 + threadIdx.x) * 4;
    float4 v = *(const float4*)(x + i);
    ushort4 o;
    o.x = f2bf(v.x); o.y = f2bf(v.y); o.z = f2bf(v.z); o.w = f2bf(v.w);
    *(ushort4*)(xb + i) = o;
}

// WT[n*512+k] = bf16(W[k*512+n]); four weight matrices in one launch (z-indexed)
__global__ void __launch_bounds__(256) k_cvt_w4(
    const float* __restrict__ W0, const float* __restrict__ W1,
    const float* __restrict__ W2, const float* __restrict__ W3,
    unsigned short* __restrict__ T0, unsigned short* __restrict__ T1,
    unsigned short* __restrict__ T2, unsigned short* __restrict__ T3) {
    const int z = blockIdx.z;
    const float* W = (z == 0) ? W0 : (z == 1) ? W1 : (z == 2) ? W2 : W3;
    unsigned short* T = (z == 0) ? T0 : (z == 1) ? T1 : (z == 2) ? T2 : T3;
    int idx = blockIdx.x * 256 + threadIdx.x;  // 0..262143
    int n = idx >> 9, k = idx & 511;
    T[idx] = f2bf(W[k * 512 + n]);
}

// ---------------------------------------------------------------- QKV proj
// C = Xb @ W (A.B^T form with WT, bf16 MFMA), 128x128 tile, BK=32.
// z=0: Q fp8 row-major [b*N][U]
// z=1: K8 fp8 layout [b][d>>3][key][d&7]   (flash K-tile staging friendly)
// z=2: V8 fp8 layout [b][key>>3][d][key&7] (flash V-tile staging friendly)
__global__ void __launch_bounds__(256, 2) k_proj(
    const unsigned short* __restrict__ Xb,
    const unsigned short* __restrict__ WqT, const unsigned short* __restrict__ WkT,
    const unsigned short* __restrict__ WvT,
    const float* __restrict__ bq, const float* __restrict__ bk, const float* __restrict__ bv,
    unsigned char* __restrict__ Q, unsigned char* __restrict__ K8,
    unsigned char* __restrict__ V8)
{
    __shared__ __align__(16) unsigned short As[128 * 32];
    __shared__ __align__(16) unsigned short Bs[128 * 32];
    const int z = blockIdx.z;
    const unsigned short* WT = (z == 0) ? WqT : (z == 1) ? WkT : WvT;
    const float* bias = (z == 0) ? bq : (z == 1) ? bk : bv;
    const int t = threadIdx.x, wave = t >> 6, lane = t & 63;
    const int quad = lane >> 4, l16 = lane & 15;
    const int m0 = blockIdx.x * 128, n0 = blockIdx.y * 128;
    const int wm = wave >> 1, wn = wave & 1;

    const int srow = wave * 32 + (lane >> 2);
    const int scol = (lane & 3) * 8;
    const unsigned short* gA = Xb + (size_t)(m0 + srow) * UU + scol;
    const unsigned short* gB = WT + (size_t)(n0 + srow) * UU + scol;
    unsigned short* lA = As + wave * 1024;
    unsigned short* lB = Bs + wave * 1024;

    floatx4 acc[4][4] = {};

    for (int k0 = 0; k0 < UU; k0 += 32) {
        GLL16(gA + k0, lA);
        GLL16(gA + k0 + 16 * UU, lA + 512);
        GLL16(gB + k0, lB);
        GLL16(gB + k0 + 16 * UU, lB + 512);
        __syncthreads();
        short8 a[4], b[4];
        #pragma unroll
        for (int i = 0; i < 4; i++)
            a[i] = *(const short8*)(As + (wm * 64 + i * 16 + l16) * 32 + quad * 8);
        #pragma unroll
        for (int j = 0; j < 4; j++)
            b[j] = *(const short8*)(Bs + (wn * 64 + j * 16 + l16) * 32 + quad * 8);
        #pragma unroll
        for (int i = 0; i < 4; i++)
            #pragma unroll
            for (int j = 0; j < 4; j++)
                acc[i][j] = mfma16(a[i], b[j], acc[i][j]);
        __syncthreads();
    }

    #pragma unroll
    for (int j = 0; j < 4; j++) {
        const int n = n0 + wn * 64 + j * 16 + l16;
        const float bv_ = bias[n];
        #pragma unroll
        for (int i = 0; i < 4; i++) {
            const int mb = m0 + wm * 64 + i * 16 + quad * 4;
            const int bb = mb >> 12, tok = mb & (NN - 1);
            if (z == 0) {
                #pragma unroll
                for (int r = 0; r < 4; r++)
                    Q[(size_t)(mb + r) * UU + n] = f2fp8(acc[i][j][r] + bv_);
            } else if (z == 1) {
                const size_t base = (size_t)bb * NN * UU + (size_t)(n >> 3) * (NN * 8)
                                  + (size_t)tok * 8 + (n & 7);
                #pragma unroll
                for (int r = 0; r < 4; r++)
                    K8[base + (size_t)r * 8] = f2fp8(acc[i][j][r] + bv_);
            } else {
                uchar4 o8;
                o8.x = f2fp8(acc[i][j][0] + bv_);
                o8.y = f2fp8(acc[i][j][1] + bv_);
                o8.z = f2fp8(acc[i][j][2] + bv_);
                o8.w = f2fp8(acc[i][j][3] + bv_);
                *(uchar4*)(V8 + (size_t)bb * NN * UU + (size_t)(tok >> 3) * (UU * 8)
                           + (size_t)n * 8 + (tok & 7)) = o8;
            }
        }
    }
}

// ---------------------------------------------------------------- flash attention
// BM=32 q rows/block, 4 waves (256 thr), grid 128x4 = 512 blocks -> 2 blocks/CU
// (LDS ~75 KB). Same waves/CU as before, but the two resident blocks' barriers
// are INDEPENDENT: one block's drain overlaps the other's compute.
// All inner code identical to the verified R11 fp8 kernel:
//   S phase : wave(qt,kh) = 16q x 32k x 512d, 16x16x32 fp8 MFMA.
//   PV phase: wave dg owns 32q x 128d, 32x32x16 fp8 MFMA (qh==0 form).
//   V(kt) staged at loop top; K(kt+64) right after post-S barrier.
__global__ void __launch_bounds__(256, 2) k_flash(
    const unsigned char* __restrict__ Q,
    const unsigned char* __restrict__ K8,
    const unsigned char* __restrict__ V8,
    unsigned short* __restrict__ ctx)
{
    __shared__ __align__(16) unsigned char Ks[64 * 64 * 8];   // [dc 64][key 64][kk 8] fp8 32 KB
    __shared__ __align__(16) unsigned char Vs[8 * 512 * 8];   // [kc 8][d 512][kk 8] fp8  32 KB
    __shared__ __align__(16) float S_lds[32 * 68];            // 8.5 KB
    __shared__ __align__(16) unsigned char P_lds8[32 * 72];   // 2.25 KB
    __shared__ float m_lds[32], l_lds[32], a_lds[32];

    const int b = blockIdx.y;
    const int q0 = blockIdx.x * 32;
    const int t = threadIdx.x;
    const int wave = t >> 6, lane = t & 63, quad = lane >> 4, l16 = lane & 15;
    const int qt = wave >> 1;   // S: q-tile 0..1 (16 rows)
    const int kh = wave & 1;    // S: key half 0..1
    const int dg = wave;        // PV/epilogue: 128-d group 0..3
    const int l31 = lane & 31, hi = lane >> 5;

    if (t < 32) { m_lds[t] = -INFINITY; l_lds[t] = 0.f; }

    // Q fragments for this wave's 16 q-rows (S mapping), all 512 dims, fp8 (32 VGPR)
    const unsigned char* qp = Q + (size_t)(b * NN + q0 + qt * 16 + l16) * UU + quad * 8;
    long qf[16];
    #pragma unroll
    for (int kk = 0; kk < 16; kk++) qf[kk] = *(const long*)(qp + kk * 32);

    const unsigned char* K8b = K8 + (size_t)b * NN * UU;
    const unsigned char* V8b = V8 + (size_t)b * NN * UU;

    // prologue: stage K(0) — 32 KB with 4 waves: 8 GLL16/wave, 2 dc rows each
    #pragma unroll
    for (int j = 0; j < 8; j++) {
        const int dc = wave * 16 + j * 2;
        GLL16(K8b + (size_t)(dc + (lane >> 5)) * (NN * 8) + (size_t)((lane & 31) * 2) * 8,
              Ks + dc * 512 + lane * 16);
    }

    // PV accumulators: four 32x32 tiles (q rows q0.., d cols dg*128 + tt*32..)
    floatx16 o[4] = {};
    const float sscale = 0.04419417382415922f * 1.4426950408889634f;  // 1/sqrt(512)*log2(e)

    __syncthreads();  // K(0) staged, m/l init visible

    for (int kt = 0; kt < NN; kt += 64) {
        // stage V(kt): contiguous 32 KB fp8, 8 GLL16/wave
        #pragma unroll
        for (int j = 0; j < 8; j++) {
            const int c = wave * 8 + j;
            GLL16(V8b + (size_t)kt * 512 + (size_t)c * 1024 + lane * 16,
                  Vs + c * 1024 + lane * 16);
        }

        // ---- S = Q K^T from LDS: wave computes 16 q-rows x 32 keys, fp8 MFMA
        floatx4 s0 = {}, s1 = {};
        #pragma unroll
        for (int kk = 0; kk < 16; kk++) {
            const unsigned char* kb = Ks + ((kk * 4 + quad) * 64 + kh * 32 + l16) * 8;
            long b0 = *(const long*)(kb);
            long b1 = *(const long*)(kb + 128);   // +16 keys
            s0 = mfma16f8(qf[kk], b0, s0);
            s1 = mfma16f8(qf[kk], b1, s1);
        }
        #pragma unroll
        for (int i = 0; i < 4; i++) {
            S_lds[(qt * 16 + quad * 4 + i) * 68 + kh * 32 + l16]      = s0[i] * sscale;
            S_lds[(qt * 16 + quad * 4 + i) * 68 + kh * 32 + 16 + l16] = s1[i] * sscale;
        }
        __syncthreads();   // S visible; V(kt) drained; Ks reads done

        // stage K(kt+64) now — drains under stats+PV before loop-end barrier
        if (kt + 64 < NN) {
            #pragma unroll
            for (int j = 0; j < 8; j++) {
                const int dc = wave * 16 + j * 2;
                GLL16(K8b + (size_t)(dc + (lane >> 5)) * (NN * 8)
                          + (size_t)(kt + 64 + (lane & 31) * 2) * 8,
                      Ks + dc * 512 + lane * 16);
            }
        }

        // ---- online softmax stats (8 threads per row, 8 cols each; 32 rows)
        {
            const int row = t >> 3, c8 = (t & 7) * 8;
            const float4* sp = (const float4*)(S_lds + row * 68 + c8);
            float4 va = sp[0], vb = sp[1];
            float mx = fmaxf(fmaxf(fmaxf(va.x, va.y), fmaxf(va.z, va.w)),
                             fmaxf(fmaxf(vb.x, vb.y), fmaxf(vb.z, vb.w)));
            mx = fmaxf(mx, __shfl_xor(mx, 1, 8));
            mx = fmaxf(mx, __shfl_xor(mx, 2, 8));
            mx = fmaxf(mx, __shfl_xor(mx, 4, 8));
            const float m_old = m_lds[row];
            const float m_new = fmaxf(m_old, mx);
            float p[8] = { exp2f(va.x - m_new), exp2f(va.y - m_new),
                           exp2f(va.z - m_new), exp2f(va.w - m_new),
                           exp2f(vb.x - m_new), exp2f(vb.y - m_new),
                           exp2f(vb.z - m_new), exp2f(vb.w - m_new) };
            unsigned long long pv8 = 0ull; float sum = 0.f;
            #pragma unroll
            for (int j = 0; j < 8; j++) {
                unsigned char uc = f2fp8(p[j]);
                pv8 |= (unsigned long long)uc << (8 * j);
                sum += fp82f(uc);   // sum what PV actually uses
            }
            *(unsigned long long*)(P_lds8 + row * 72 + c8) = pv8;
            sum += __shfl_xor(sum, 1, 8);
            sum += __shfl_xor(sum, 2, 8);
            sum += __shfl_xor(sum, 4, 8);
            if ((t & 7) == 0) {
                const float alpha = exp2f(m_old - m_new);
                a_lds[row] = alpha;
                m_lds[row] = m_new;
                l_lds[row] = l_lds[row] * alpha + sum;
            }
        }
        __syncthreads();   // P/stats visible

        // ---- O = O*alpha + P @ V, 32x32x16 fp8 MFMA (verified layout, qh==0).
        // A-frag: lane holds P[l31][k=ks*16+hi*8+j] (8 bytes);
        // B-frag: V[k][d0+l31] (8 bytes); D mapping row=(r&3)+8*(r>>2)+4*hi, col=l31.
        {
            float4 al4[4];
            #pragma unroll
            for (int r1 = 0; r1 < 4; r1++)
                al4[r1] = *(const float4*)(a_lds + hi * 4 + r1 * 8);
            #pragma unroll
            for (int tt = 0; tt < 4; tt++)
                #pragma unroll
                for (int r = 0; r < 16; r++)
                    o[tt][r] *= al4[r >> 2][r & 3];

            long aP[4];
            #pragma unroll
            for (int ks = 0; ks < 4; ks++)
                aP[ks] = *(const long*)(P_lds8 + l31 * 72 + ks * 16 + hi * 8);
            #pragma unroll
            for (int ks = 0; ks < 4; ks++) {
                #pragma unroll
                for (int tt = 0; tt < 4; tt++) {
                    const int d0 = dg * 128 + tt * 32;
                    long bV = *(const long*)(Vs + (ks * 2 + hi) * 4096
                                             + (size_t)(d0 + l31) * 8);
                    o[tt] = mfma32f8(aP[ks], bV, o[tt]);
                }
            }
        }
        __syncthreads();   // PV reads done; K(kt+64) drained
    }

    // ---- epilogue: normalize, store ctx bf16 [B*N][U]
    float4 li4[4];
    #pragma unroll
    for (int r1 = 0; r1 < 4; r1++) {
        float4 lv = *(const float4*)(l_lds + hi * 4 + r1 * 8);
        li4[r1] = make_float4(1.f / lv.x, 1.f / lv.y, 1.f / lv.z, 1.f / lv.w);
    }
    #pragma unroll
    for (int tt = 0; tt < 4; tt++) {
        const int d0 = dg * 128 + tt * 32;
        #pragma unroll
        for (int r = 0; r < 16; r++) {
            const int row = q0 + (r & 3) + 8 * (r >> 2) + 4 * hi;
            ctx[(size_t)(b * NN + row) * UU + d0 + l31]
                = f2bf(o[tt][r] * ((const float*)&li4[r >> 2])[r & 3]);
        }
    }
}

// ---------------------------------------------------------------- out proj + residual
__global__ void __launch_bounds__(256, 2) k_out(
    const unsigned short* __restrict__ Cx,
    const unsigned short* __restrict__ WpT,
    const float* __restrict__ bp,
    const float* __restrict__ x,
    float* __restrict__ out)
{
    __shared__ __align__(16) unsigned short As[128 * 32];
    __shared__ __align__(16) unsigned short Bs[128 * 32];
    const int t = threadIdx.x, wave = t >> 6, lane = t & 63;
    const int quad = lane >> 4, l16 = lane & 15;
    const int m0 = blockIdx.x * 128, n0 = blockIdx.y * 128;
    const int wm = wave >> 1, wn = wave & 1;
    const int srow = wave * 32 + (lane >> 2);
    const int scol = (lane & 3) * 8;
    const unsigned short* gA = Cx + (size_t)(m0 + srow) * UU + scol;
    const unsigned short* gB = WpT + (size_t)(n0 + srow) * UU + scol;
    unsigned short* lA = As + wave * 1024;
    unsigned short* lB = Bs + wave * 1024;

    floatx4 acc[4][4] = {};

    for (int k0 = 0; k0 < UU; k0 += 32) {
        GLL16(gA + k0, lA);
        GLL16(gA + k0 + 16 * UU, lA + 512);
        GLL16(gB + k0, lB);
        GLL16(gB + k0 + 16 * UU, lB + 512);
        __syncthreads();
        short8 a[4], b[4];
        #pragma unroll
        for (int i = 0; i < 4; i++)
            a[i] = *(const short8*)(As + (wm * 64 + i * 16 + l16) * 32 + quad * 8);
        #pragma unroll
        for (int j = 0; j < 4; j++)
            b[j] = *(const short8*)(Bs + (wn * 64 + j * 16 + l16) * 32 + quad * 8);
        #pragma unroll
        for (int i = 0; i < 4; i++)
            #pragma unroll
            for (int j = 0; j < 4; j++)
                acc[i][j] = mfma16(a[i], b[j], acc[i][j]);
        __syncthreads();
    }

    #pragma unroll
    for (int j = 0; j < 4; j++) {
        const int n = n0 + wn * 64 + j * 16 + l16;
        const float bv_ = bp[n];
        #pragma unroll
        for (int i = 0; i < 4; i++) {
            const int mb = m0 + wm * 64 + i * 16 + quad * 4;
            #pragma unroll
            for (int r = 0; r < 4; r++) {
                const size_t idx = (size_t)(mb + r) * UU + n;
                out[idx] = acc[i][j][r] + bv_ + x[idx];
            }
        }
    }
}

// ---------------------------------------------------------------- launch
extern "C" void kernel_launch(void* const* d_in, const int* in_sizes, int n_in,
                              void* d_out, int out_size, void* d_ws, size_t ws_size,
                              hipStream_t stream)
{
    const float* x  = (const float*)d_in[0];
    const float* Wq = (const float*)d_in[1];
    const float* bq = (const float*)d_in[2];
    const float* Wk = (const float*)d_in[3];
    const float* bk = (const float*)d_in[4];
    const float* Wv = (const float*)d_in[5];
    const float* bv = (const float*)d_in[6];
    const float* Wp = (const float*)d_in[7];
    const float* bp = (const float*)d_in[8];
    float* out = (float*)d_out;

    char* ws = (char*)d_ws;
    unsigned short* Xb  = (unsigned short*)(ws);              // 16 MB  bf16 x
    unsigned short* WqT = (unsigned short*)(ws + 16777216);   // 512 KB each
    unsigned short* WkT = (unsigned short*)(ws + 17301504);
    unsigned short* WvT = (unsigned short*)(ws + 17825792);
    unsigned short* WpT = (unsigned short*)(ws + 18350080);
    unsigned char*  Qm  = (unsigned char*)(ws + 18874368);    //  8 MB fp8 [b*N][U]
    unsigned char*  K8m = (unsigned char*)(ws + 35651584);    //  8 MB fp8 [b][d>>3][key][d&7]
    unsigned char*  V8m = (unsigned char*)(ws + 52428800);    //  8 MB fp8 [b][key>>3][d][key&7]
    unsigned short* Cx  = (unsigned short*)(ws + 69206016);   // 16 MB [b*N][U]

    hipLaunchKernelGGL(k_cvt_x, dim3(8192), dim3(256), 0, stream, x, Xb);
    hipLaunchKernelGGL(k_cvt_w4, dim3(1024, 1, 4), dim3(256), 0, stream,
                       Wq, Wk, Wv, Wp, WqT, WkT, WvT, WpT);
    hipLaunchKernelGGL(k_proj, dim3(128, 4, 3), dim3(256), 0, stream,
                       Xb, WqT, WkT, WvT, bq, bk, bv, Qm, K8m, V8m);
    hipLaunchKernelGGL(k_flash, dim3(128, 4), dim3(256), 0, stream, Qm, K8m, V8m, Cx);
    hipLaunchKernelGGL(k_out, dim3(128, 4), dim3(256), 0, stream, Cx, WpT, bp, x, out);
}

// Round 15
// 335.507 us; speedup vs baseline: 1.0325x; 1.0325x over previous
//
#include <hip/hip_runtime.h>
#include <hip/hip_bf16.h>
#include <math.h>

#define NB 4
#define NN 4096
#define UU 512

using short8   = __attribute__((ext_vector_type(8))) short;
using bf16x8   = __attribute__((ext_vector_type(8))) __bf16;
using floatx4  = __attribute__((ext_vector_type(4))) float;
using floatx16 = __attribute__((ext_vector_type(16))) float;

__device__ __forceinline__ floatx4 mfma16(short8 a, short8 b, floatx4 c) {
    return __builtin_amdgcn_mfma_f32_16x16x32_bf16(
        __builtin_bit_cast(bf16x8, a), __builtin_bit_cast(bf16x8, b), c, 0, 0, 0);
}
__device__ __forceinline__ floatx4 mfma16f8(long a, long b, floatx4 c) {
    return __builtin_amdgcn_mfma_f32_16x16x32_fp8_fp8(a, b, c, 0, 0, 0);
}
__device__ __forceinline__ floatx16 mfma32f8(long a, long b, floatx16 c) {
    return __builtin_amdgcn_mfma_f32_32x32x16_fp8_fp8(a, b, c, 0, 0, 0);
}

__device__ __forceinline__ unsigned short f2bf(float f) {
    union { float f; unsigned u; } v; v.f = f;
    return (unsigned short)((v.u + 0x7fffu + ((v.u >> 16) & 1u)) >> 16);
}
__device__ __forceinline__ float bf2f(unsigned short s) {
    union { unsigned u; float f; } v; v.u = ((unsigned)s) << 16; return v.f;
}
// HW fp8 e4m3 conversion (gfx940+). Word-select/byte-select must be literals.
template <bool HI>
__device__ __forceinline__ int cvtpk8(float a, float b, int old) {
    return __builtin_amdgcn_cvt_pk_fp8_f32(a, b, old, HI);
}

#define GLL16(gp, lp) __builtin_amdgcn_global_load_lds( \
    (const __attribute__((address_space(1))) void*)(gp), \
    (__attribute__((address_space(3))) void*)(lp), 16, 0, 0)

// ---------------------------------------------------------------- converts
__global__ void __launch_bounds__(256) k_cvt_x(const float* __restrict__ x,
                                               unsigned short* __restrict__ xb) {
    int i = (blockIdx.x * 256 + threadIdx.x) * 4;
    float4 v = *(const float4*)(x + i);
    ushort4 o;
    o.x = f2bf(v.x); o.y = f2bf(v.y); o.z = f2bf(v.z); o.w = f2bf(v.w);
    *(ushort4*)(xb + i) = o;
}

// WT[n*512+k] = bf16(W[k*512+n]); four weight matrices in one launch (z-indexed)
__global__ void __launch_bounds__(256) k_cvt_w4(
    const float* __restrict__ W0, const float* __restrict__ W1,
    const float* __restrict__ W2, const float* __restrict__ W3,
    unsigned short* __restrict__ T0, unsigned short* __restrict__ T1,
    unsigned short* __restrict__ T2, unsigned short* __restrict__ T3) {
    const int z = blockIdx.z;
    const float* W = (z == 0) ? W0 : (z == 1) ? W1 : (z == 2) ? W2 : W3;
    unsigned short* T = (z == 0) ? T0 : (z == 1) ? T1 : (z == 2) ? T2 : T3;
    int idx = blockIdx.x * 256 + threadIdx.x;  // 0..262143
    int n = idx >> 9, k = idx & 511;
    T[idx] = f2bf(W[k * 512 + n]);
}

// ---------------------------------------------------------------- QKV proj
// C = Xb @ W (A.B^T form with WT, bf16 MFMA), 128x128 tile, BK=32.
// z=0: Q fp8 row-major [b*N][U]
// z=1: K8 fp8 layout [b][d>>3][key][d&7]   (flash K-tile staging friendly)
// z=2: V8 fp8 layout [b][key>>3][d][key&7] (flash V-tile staging friendly)
__global__ void __launch_bounds__(256, 2) k_proj(
    const unsigned short* __restrict__ Xb,
    const unsigned short* __restrict__ WqT, const unsigned short* __restrict__ WkT,
    const unsigned short* __restrict__ WvT,
    const float* __restrict__ bq, const float* __restrict__ bk, const float* __restrict__ bv,
    unsigned char* __restrict__ Q, unsigned char* __restrict__ K8,
    unsigned char* __restrict__ V8)
{
    __shared__ __align__(16) unsigned short As[128 * 32];
    __shared__ __align__(16) unsigned short Bs[128 * 32];
    const int z = blockIdx.z;
    const unsigned short* WT = (z == 0) ? WqT : (z == 1) ? WkT : WvT;
    const float* bias = (z == 0) ? bq : (z == 1) ? bk : bv;
    const int t = threadIdx.x, wave = t >> 6, lane = t & 63;
    const int quad = lane >> 4, l16 = lane & 15;
    const int m0 = blockIdx.x * 128, n0 = blockIdx.y * 128;
    const int wm = wave >> 1, wn = wave & 1;

    const int srow = wave * 32 + (lane >> 2);
    const int scol = (lane & 3) * 8;
    const unsigned short* gA = Xb + (size_t)(m0 + srow) * UU + scol;
    const unsigned short* gB = WT + (size_t)(n0 + srow) * UU + scol;
    unsigned short* lA = As + wave * 1024;
    unsigned short* lB = Bs + wave * 1024;

    floatx4 acc[4][4] = {};

    for (int k0 = 0; k0 < UU; k0 += 32) {
        GLL16(gA + k0, lA);
        GLL16(gA + k0 + 16 * UU, lA + 512);
        GLL16(gB + k0, lB);
        GLL16(gB + k0 + 16 * UU, lB + 512);
        __syncthreads();
        short8 a[4], b[4];
        #pragma unroll
        for (int i = 0; i < 4; i++)
            a[i] = *(const short8*)(As + (wm * 64 + i * 16 + l16) * 32 + quad * 8);
        #pragma unroll
        for (int j = 0; j < 4; j++)
            b[j] = *(const short8*)(Bs + (wn * 64 + j * 16 + l16) * 32 + quad * 8);
        #pragma unroll
        for (int i = 0; i < 4; i++)
            #pragma unroll
            for (int j = 0; j < 4; j++)
                acc[i][j] = mfma16(a[i], b[j], acc[i][j]);
        __syncthreads();
    }

    #pragma unroll
    for (int j = 0; j < 4; j++) {
        const int n = n0 + wn * 64 + j * 16 + l16;
        const float bv_ = bias[n];
        #pragma unroll
        for (int i = 0; i < 4; i++) {
            const int mb = m0 + wm * 64 + i * 16 + quad * 4;
            const int bb = mb >> 12, tok = mb & (NN - 1);
            // HW packed fp8 convert: 2 instrs for 4 values
            int d = cvtpk8<false>(acc[i][j][0] + bv_, acc[i][j][1] + bv_, 0);
            d     = cvtpk8<true>(acc[i][j][2] + bv_, acc[i][j][3] + bv_, d);
            if (z == 0) {
                #pragma unroll
                for (int r = 0; r < 4; r++)
                    Q[(size_t)(mb + r) * UU + n]
                        = (unsigned char)(((unsigned)d >> (8 * r)) & 0xffu);
            } else if (z == 1) {
                const size_t base = (size_t)bb * NN * UU + (size_t)(n >> 3) * (NN * 8)
                                  + (size_t)tok * 8 + (n & 7);
                #pragma unroll
                for (int r = 0; r < 4; r++)
                    K8[base + (size_t)r * 8]
                        = (unsigned char)(((unsigned)d >> (8 * r)) & 0xffu);
            } else {
                *(unsigned int*)(V8 + (size_t)bb * NN * UU + (size_t)(tok >> 3) * (UU * 8)
                                 + (size_t)n * 8 + (tok & 7)) = (unsigned)d;
            }
        }
    }
}

// ---------------------------------------------------------------- flash attention
// R11 structure (verified 202 us): 8 waves, BM=64 q rows/block, BN=64 keys/iter,
// all of Q/K/P/V in fp8 e4m3; 1 block/CU.
//   S phase : wave(qt,kh) = 16q x 32k x 512d, 16x16x32 fp8 MFMA.
//   PV phase: wave(qh,dg) owns 32q x 128d, 32x32x16 fp8 MFMA.
//   V(kt) staged at loop top; K(kt+64) right after post-S barrier.
// This round: HW cvt_pk_fp8 in stats (~12 VALU ops vs ~200 software), and
// O-rescale skipped when all alphas == 1 (exact).
__global__ void __launch_bounds__(512, 1) k_flash(
    const unsigned char* __restrict__ Q,
    const unsigned char* __restrict__ K8,
    const unsigned char* __restrict__ V8,
    unsigned short* __restrict__ ctx)
{
    __shared__ __align__(16) unsigned char Ks[64 * 64 * 8];   // [dc 64][key 64][kk 8] fp8 32 KB
    __shared__ __align__(16) unsigned char Vs[8 * 512 * 8];   // [kc 8][d 512][kk 8] fp8  32 KB
    __shared__ __align__(16) float S_lds[64 * 68];
    __shared__ __align__(16) unsigned char P_lds8[64 * 72];   // fp8 P, row stride 72 B
    __shared__ float m_lds[64], l_lds[64], a_lds[64];

    const int b = blockIdx.y;
    const int q0 = blockIdx.x * 64;
    const int t = threadIdx.x;
    const int wave = t >> 6, lane = t & 63, quad = lane >> 4, l16 = lane & 15;
    const int qt = wave >> 1;   // S: q-tile 0..3 (16 rows)
    const int kh = wave & 1;    // S: key half 0..1
    const int qh = wave >> 2;   // PV/epilogue: 32-q half 0..1
    const int dg = wave & 3;    // PV/epilogue: 128-d group 0..3
    const int l31 = lane & 31, hi = lane >> 5;

    if (t < 64) { m_lds[t] = -INFINITY; l_lds[t] = 0.f; }

    // Q fragments for this wave's 16 q-rows (S mapping), all 512 dims, fp8 (32 VGPR)
    const unsigned char* qp = Q + (size_t)(b * NN + q0 + qt * 16 + l16) * UU + quad * 8;
    long qf[16];
    #pragma unroll
    for (int kk = 0; kk < 16; kk++) qf[kk] = *(const long*)(qp + kk * 32);

    const unsigned char* K8b = K8 + (size_t)b * NN * UU;
    const unsigned char* V8b = V8 + (size_t)b * NN * UU;

    // prologue: stage K(0) — 32 KB; per instr: 2 dc rows, per-lane global source
    #pragma unroll
    for (int j = 0; j < 4; j++) {
        const int dc = wave * 8 + j * 2;
        GLL16(K8b + (size_t)(dc + (lane >> 5)) * (NN * 8) + (size_t)((lane & 31) * 2) * 8,
              Ks + dc * 512 + lane * 16);
    }

    // PV accumulators: four 32x32 tiles (q rows qh*32.., d cols dg*128 + tt*32..)
    floatx16 o[4] = {};
    const float sscale = 0.04419417382415922f * 1.4426950408889634f;  // 1/sqrt(512)*log2(e)

    __syncthreads();  // K(0) staged, m/l init visible

    for (int kt = 0; kt < NN; kt += 64) {
        // stage V(kt): contiguous 32 KB fp8 at V8b + kt*512 bytes
        #pragma unroll
        for (int j = 0; j < 4; j++) {
            const int c = wave * 4 + j;
            GLL16(V8b + (size_t)kt * 512 + (size_t)c * 1024 + lane * 16,
                  Vs + c * 1024 + lane * 16);
        }

        // ---- S = Q K^T from LDS: wave computes 16 q-rows x 32 keys, fp8 MFMA
        floatx4 s0 = {}, s1 = {};
        #pragma unroll
        for (int kk = 0; kk < 16; kk++) {
            const unsigned char* kb = Ks + ((kk * 4 + quad) * 64 + kh * 32 + l16) * 8;
            long b0 = *(const long*)(kb);
            long b1 = *(const long*)(kb + 128);   // +16 keys
            s0 = mfma16f8(qf[kk], b0, s0);
            s1 = mfma16f8(qf[kk], b1, s1);
        }
        #pragma unroll
        for (int i = 0; i < 4; i++) {
            S_lds[(qt * 16 + quad * 4 + i) * 68 + kh * 32 + l16]      = s0[i] * sscale;
            S_lds[(qt * 16 + quad * 4 + i) * 68 + kh * 32 + 16 + l16] = s1[i] * sscale;
        }
        __syncthreads();   // S visible; V(kt) drained; Ks reads done

        // stage K(kt+64) now — drains under stats+PV before loop-end barrier
        if (kt + 64 < NN) {
            #pragma unroll
            for (int j = 0; j < 4; j++) {
                const int dc = wave * 8 + j * 2;
                GLL16(K8b + (size_t)(dc + (lane >> 5)) * (NN * 8)
                          + (size_t)(kt + 64 + (lane & 31) * 2) * 8,
                      Ks + dc * 512 + lane * 16);
            }
        }

        // ---- online softmax stats (8 threads per row, 8 cols each)
        {
            const int row = t >> 3, c8 = (t & 7) * 8;
            const float4* sp = (const float4*)(S_lds + row * 68 + c8);
            float4 va = sp[0], vb = sp[1];
            float mx = fmaxf(fmaxf(fmaxf(va.x, va.y), fmaxf(va.z, va.w)),
                             fmaxf(fmaxf(vb.x, vb.y), fmaxf(vb.z, vb.w)));
            mx = fmaxf(mx, __shfl_xor(mx, 1, 8));
            mx = fmaxf(mx, __shfl_xor(mx, 2, 8));
            mx = fmaxf(mx, __shfl_xor(mx, 4, 8));
            const float m_old = m_lds[row];
            const float m_new = fmaxf(m_old, mx);
            // HW packed fp8 convert: 4 cvt_pk for 8 values
            int d0 = cvtpk8<false>(exp2f(va.x - m_new), exp2f(va.y - m_new), 0);
            d0     = cvtpk8<true>(exp2f(va.z - m_new), exp2f(va.w - m_new), d0);
            int d1 = cvtpk8<false>(exp2f(vb.x - m_new), exp2f(vb.y - m_new), 0);
            d1     = cvtpk8<true>(exp2f(vb.z - m_new), exp2f(vb.w - m_new), d1);
            *(uint2*)(P_lds8 + row * 72 + c8) = make_uint2((unsigned)d0, (unsigned)d1);
            // sum what PV actually uses: HW decode, literal byte selects
            float sum = __builtin_amdgcn_cvt_f32_fp8(d0, 0)
                      + __builtin_amdgcn_cvt_f32_fp8(d0, 1)
                      + __builtin_amdgcn_cvt_f32_fp8(d0, 2)
                      + __builtin_amdgcn_cvt_f32_fp8(d0, 3)
                      + __builtin_amdgcn_cvt_f32_fp8(d1, 0)
                      + __builtin_amdgcn_cvt_f32_fp8(d1, 1)
                      + __builtin_amdgcn_cvt_f32_fp8(d1, 2)
                      + __builtin_amdgcn_cvt_f32_fp8(d1, 3);
            sum += __shfl_xor(sum, 1, 8);
            sum += __shfl_xor(sum, 2, 8);
            sum += __shfl_xor(sum, 4, 8);
            if ((t & 7) == 0) {
                const float alpha = exp2f(m_old - m_new);
                a_lds[row] = alpha;
                m_lds[row] = m_new;
                l_lds[row] = l_lds[row] * alpha + sum;
            }
        }
        __syncthreads();   // P/stats visible

        // ---- O = O*alpha + P @ V, 32x32x16 fp8 MFMA (verified layout).
        {
            float4 al4[4];
            #pragma unroll
            for (int r1 = 0; r1 < 4; r1++)
                al4[r1] = *(const float4*)(a_lds + qh * 32 + hi * 4 + r1 * 8);
            // skip the 64-multiply rescale when all alphas are exactly 1 (common case)
            bool nr = false;
            #pragma unroll
            for (int r1 = 0; r1 < 4; r1++)
                nr = nr | (al4[r1].x != 1.f) | (al4[r1].y != 1.f)
                        | (al4[r1].z != 1.f) | (al4[r1].w != 1.f);
            if (__any(nr)) {
                #pragma unroll
                for (int tt = 0; tt < 4; tt++)
                    #pragma unroll
                    for (int r = 0; r < 16; r++)
                        o[tt][r] *= al4[r >> 2][r & 3];
            }

            long aP[4];
            #pragma unroll
            for (int ks = 0; ks < 4; ks++)
                aP[ks] = *(const long*)(P_lds8 + (qh * 32 + l31) * 72 + ks * 16 + hi * 8);
            #pragma unroll
            for (int ks = 0; ks < 4; ks++) {
                #pragma unroll
                for (int tt = 0; tt < 4; tt++) {
                    const int d0 = dg * 128 + tt * 32;
                    long bV = *(const long*)(Vs + (ks * 2 + hi) * 4096
                                             + (size_t)(d0 + l31) * 8);
                    o[tt] = mfma32f8(aP[ks], bV, o[tt]);
                }
            }
        }
        __syncthreads();   // PV reads done; K(kt+64) drained
    }

    // ---- epilogue: normalize, store ctx bf16 [B*N][U]
    float4 li4[4];
    #pragma unroll
    for (int r1 = 0; r1 < 4; r1++) {
        float4 lv = *(const float4*)(l_lds + qh * 32 + hi * 4 + r1 * 8);
        li4[r1] = make_float4(1.f / lv.x, 1.f / lv.y, 1.f / lv.z, 1.f / lv.w);
    }
    #pragma unroll
    for (int tt = 0; tt < 4; tt++) {
        const int d0 = dg * 128 + tt * 32;
        #pragma unroll
        for (int r = 0; r < 16; r++) {
            const int row = q0 + qh * 32 + (r & 3) + 8 * (r >> 2) + 4 * hi;
            ctx[(size_t)(b * NN + row) * UU + d0 + l31]
                = f2bf(o[tt][r] * ((const float*)&li4[r >> 2])[r & 3]);
        }
    }
}

// ---------------------------------------------------------------- out proj + residual
__global__ void __launch_bounds__(256, 2) k_out(
    const unsigned short* __restrict__ Cx,
    const unsigned short* __restrict__ WpT,
    const float* __restrict__ bp,
    const float* __restrict__ x,
    float* __restrict__ out)
{
    __shared__ __align__(16) unsigned short As[128 * 32];
    __shared__ __align__(16) unsigned short Bs[128 * 32];
    const int t = threadIdx.x, wave = t >> 6, lane = t & 63;
    const int quad = lane >> 4, l16 = lane & 15;
    const int m0 = blockIdx.x * 128, n0 = blockIdx.y * 128;
    const int wm = wave >> 1, wn = wave & 1;
    const int srow = wave * 32 + (lane >> 2);
    const int scol = (lane & 3) * 8;
    const unsigned short* gA = Cx + (size_t)(m0 + srow) * UU + scol;
    const unsigned short* gB = WpT + (size_t)(n0 + srow) * UU + scol;
    unsigned short* lA = As + wave * 1024;
    unsigned short* lB = Bs + wave * 1024;

    floatx4 acc[4][4] = {};

    for (int k0 = 0; k0 < UU; k0 += 32) {
        GLL16(gA + k0, lA);
        GLL16(gA + k0 + 16 * UU, lA + 512);
        GLL16(gB + k0, lB);
        GLL16(gB + k0 + 16 * UU, lB + 512);
        __syncthreads();
        short8 a[4], b[4];
        #pragma unroll
        for (int i = 0; i < 4; i++)
            a[i] = *(const short8*)(As + (wm * 64 + i * 16 + l16) * 32 + quad * 8);
        #pragma unroll
        for (int j = 0; j < 4; j++)
            b[j] = *(const short8*)(Bs + (wn * 64 + j * 16 + l16) * 32 + quad * 8);
        #pragma unroll
        for (int i = 0; i < 4; i++)
            #pragma unroll
            for (int j = 0; j < 4; j++)
                acc[i][j] = mfma16(a[i], b[j], acc[i][j]);
        __syncthreads();
    }

    #pragma unroll
    for (int j = 0; j < 4; j++) {
        const int n = n0 + wn * 64 + j * 16 + l16;
        const float bv_ = bp[n];
        #pragma unroll
        for (int i = 0; i < 4; i++) {
            const int mb = m0 + wm * 64 + i * 16 + quad * 4;
            #pragma unroll
            for (int r = 0; r < 4; r++) {
                const size_t idx = (size_t)(mb + r) * UU + n;
                out[idx] = acc[i][j][r] + bv_ + x[idx];
            }
        }
    }
}

// ---------------------------------------------------------------- launch
extern "C" void kernel_launch(void* const* d_in, const int* in_sizes, int n_in,
                              void* d_out, int out_size, void* d_ws, size_t ws_size,
                              hipStream_t stream)
{
    const float* x  = (const float*)d_in[0];
    const float* Wq = (const float*)d_in[1];
    const float* bq = (const float*)d_in[2];
    const float* Wk = (const float*)d_in[3];
    const float* bk = (const float*)d_in[4];
    const float* Wv = (const float*)d_in[5];
    const float* bv = (const float*)d_in[6];
    const float* Wp = (const float*)d_in[7];
    const float* bp = (const float*)d_in[8];
    float* out = (float*)d_out;

    char* ws = (char*)d_ws;
    unsigned short* Xb  = (unsigned short*)(ws);              // 16 MB  bf16 x
    unsigned short* WqT = (unsigned short*)(ws + 16777216);   // 512 KB each
    unsigned short* WkT = (unsigned short*)(ws + 17301504);
    unsigned short* WvT = (unsigned short*)(ws + 17825792);
    unsigned short* WpT = (unsigned short*)(ws + 18350080);
    unsigned char*  Qm  = (unsigned char*)(ws + 18874368);    //  8 MB fp8 [b*N][U]
    unsigned char*  K8m = (unsigned char*)(ws + 35651584);    //  8 MB fp8 [b][d>>3][key][d&7]
    unsigned char*  V8m = (unsigned char*)(ws + 52428800);    //  8 MB fp8 [b][key>>3][d][key&7]
    unsigned short* Cx  = (unsigned short*)(ws + 69206016);   // 16 MB [b*N][U]

    hipLaunchKernelGGL(k_cvt_x, dim3(8192), dim3(256), 0, stream, x, Xb);
    hipLaunchKernelGGL(k_cvt_w4, dim3(1024, 1, 4), dim3(256), 0, stream,
                       Wq, Wk, Wv, Wp, WqT, WkT, WvT, WpT);
    hipLaunchKernelGGL(k_proj, dim3(128, 4, 3), dim3(256), 0, stream,
                       Xb, WqT, WkT, WvT, bq, bk, bv, Qm, K8m, V8m);
    hipLaunchKernelGGL(k_flash, dim3(64, 4), dim3(512), 0, stream, Qm, K8m, V8m, Cx);
    hipLaunchKernelGGL(k_out, dim3(128, 4), dim3(256), 0, stream, Cx, WpT, bp, x, out);
}